// Round 8
// baseline (124.121 us; speedup 1.0000x reference)
//
#include <hip/hip_runtime.h>

#define BB 4
#define CC 128
#define HH 96
#define WWX 96
#define RED 32
#define HW (HH * WWX)
#define NPIX (BB * HW)

// corr halo tile: 32x2 centers -> 38x8 halo
#define TX 32
#define TY 2
#define HX 38
#define NHALO (HX * 8)   // 304

// ---------------- Kernel A: 1x1 reduce conv + per-pixel recip-norm ---------
// 512 threads = 64 pixels x 8 c-groups (16 c each). cg wave-uniform -> Wr
// stays s_load. Partial acc[32] combined via padded LDS (stride 33).
__global__ __launch_bounds__(512) void reduce_kern(
    const float* __restrict__ x, const float* __restrict__ Wr,
    float* __restrict__ feat, float* __restrict__ rnorms) {
  __shared__ float part[7][64][33];  // 59136 B
  int lane = threadIdx.x & 63;
  int cg = __builtin_amdgcn_readfirstlane(threadIdx.x >> 6);  // 0..7
  int pix = blockIdx.x * 64 + lane;
  int b = pix / HW;
  int p = pix - b * HW;
  const float* xp = x + (size_t)b * CC * HW + p;

  float acc[RED];
#pragma unroll
  for (int r = 0; r < RED; ++r) acc[r] = 0.f;

#pragma unroll 8
  for (int i = 0; i < CC / 8; ++i) {
    int c = cg * (CC / 8) + i;
    float xv = xp[(size_t)c * HW];  // coalesced 256B across 64 lanes
#pragma unroll
    for (int r = 0; r < RED; ++r) acc[r] = fmaf(Wr[r * CC + c], xv, acc[r]);
  }

  if (cg != 0) {
#pragma unroll
    for (int r = 0; r < RED; ++r) part[cg - 1][lane][r] = acc[r];
  }
  __syncthreads();
  if (cg == 0) {
#pragma unroll
    for (int g = 0; g < 7; ++g)
#pragma unroll
      for (int r = 0; r < RED; ++r) acc[r] += part[g][lane][r];

    float ss = 0.f;
#pragma unroll
    for (int r = 0; r < RED; ++r) ss = fmaf(acc[r], acc[r], ss);
    float n = sqrtf(ss);
    // reciprocal norm; eps-clamped denominator never binds for real data
    rnorms[pix] = (n > 1e-6f) ? __builtin_amdgcn_rcpf(n) : 0.f;

    float4* fo = (float4*)(feat + (size_t)pix * RED);
#pragma unroll
    for (int r4 = 0; r4 < RED / 4; ++r4)
      fo[r4] = make_float4(acc[4 * r4], acc[4 * r4 + 1], acc[4 * r4 + 2], acc[4 * r4 + 3]);
  }
}

// ------------- Kernel B: fused cosine-attention + 1x1 proj + residual -------
// 512 thr = 64 centers x 8-lane octets (4 ch each). Halo feat+rnorm staged in
// LDS (zeros for OOB: dot=0, rn=0 -> sim=0 -> w=1 = exact zero-pad semantics).
// Octet reads 128B contiguous per neighbor -> conflict-free. No softmax
// max-pass (|cos|<=1). cbuf aliases fbuf (saves LDS); phase 2: 8 c-groups.
__global__ __launch_bounds__(512) void corr_kern(
    const float* __restrict__ x, const float* __restrict__ Wp,
    const float* __restrict__ feat, const float* __restrict__ rnorms,
    float* __restrict__ out) {
  __shared__ float fbuf[NHALO * RED];  // 38912 B; reused as cbuf[64][33] later
  __shared__ float nbuf[NHALO];        // 1216 B   (total 40128 B)
  float* cbuf = fbuf;
  int tid = threadIdx.x;
  int b = blockIdx.z;
  int bx = blockIdx.x * TX, by = blockIdx.y * TY;

  // ---- stage halo ----
  for (int s = tid; s < NHALO * 8; s += 512) {
    int px = s >> 3, part = s & 7;
    int hy = px / HX, hx = px - hy * HX;
    int gy = by - 3 + hy, gx = bx - 3 + hx;
    float4 v = make_float4(0.f, 0.f, 0.f, 0.f);
    if ((unsigned)gy < HH && (unsigned)gx < WWX)
      v = *(const float4*)(feat + (size_t)(b * HW + gy * WWX + gx) * RED + part * 4);
    *(float4*)(fbuf + px * RED + part * 4) = v;
  }
  for (int n = tid; n < NHALO; n += 512) {
    int hy = n / HX, hx = n - hy * HX;
    int gy = by - 3 + hy, gx = bx - 3 + hx;
    nbuf[n] = ((unsigned)gy < HH && (unsigned)gx < WWX)
                  ? rnorms[b * HW + gy * WWX + gx] : 0.f;
  }
  __syncthreads();

  // ---- phase 1: attention ----
  int og = tid & 7;   // channel octet lane: 4 ch each
  int q = tid >> 3;   // center 0..63
  int px1 = q & 31, py1 = q >> 5;
  int hidx = (py1 + 3) * HX + (px1 + 3);

  float4 fv = *(const float4*)(fbuf + hidx * RED + og * 4);
  float rc = nbuf[hidx];
  float f0 = fv.x * rc, f1 = fv.y * rc, f2 = fv.z * rc, f3 = fv.w * rc;

  float c0 = 0.f, c1 = 0.f, c2 = 0.f, c3 = 0.f;
  float l = 0.f;

#pragma unroll
  for (int dy = -3; dy <= 3; ++dy) {
#pragma unroll
    for (int dx = -3; dx <= 3; ++dx) {
      int ho = hidx + dy * HX + dx;
      float4 v = *(const float4*)(fbuf + ho * RED + og * 4);
      float dot = f0 * v.x;
      dot = fmaf(f1, v.y, dot);
      dot = fmaf(f2, v.z, dot);
      dot = fmaf(f3, v.w, dot);
      dot += __shfl_xor(dot, 1);
      dot += __shfl_xor(dot, 2);
      dot += __shfl_xor(dot, 4);  // full 32-ch dot in all 8 octet lanes
      float sim = dot * nbuf[ho];
      float wgt = __expf(sim);
      l += wgt;
      c0 = fmaf(wgt, v.x, c0);
      c1 = fmaf(wgt, v.y, c1);
      c2 = fmaf(wgt, v.z, c2);
      c3 = fmaf(wgt, v.w, c3);
    }
  }

  __syncthreads();  // fbuf reads done before aliased cbuf writes
  float invl = __builtin_amdgcn_rcpf(l);
  {
    float* cb = cbuf + q * 33 + og * 4;
    cb[0] = c0 * invl; cb[1] = c1 * invl; cb[2] = c2 * invl; cb[3] = c3 * invl;
  }
  __syncthreads();

  // ---- phase 2: 1x1 proj + residual ----
  int p2 = tid & 63;
  int cg = __builtin_amdgcn_readfirstlane(tid >> 6);  // 0..7, wave-uniform
  int px2 = p2 & 31, py2 = p2 >> 5;
  int pp = (by + py2) * WWX + bx + px2;

  float cr[RED];
#pragma unroll
  for (int r = 0; r < RED; ++r) cr[r] = cbuf[p2 * 33 + r];  // 2-way max banks

  const float* xc = x + (size_t)b * CC * HW + pp;
  float* oc = out + (size_t)b * CC * HW + pp;
#pragma unroll 4
  for (int i = 0; i < CC / 8; ++i) {
    int c = cg * (CC / 8) + i;
    float a = xc[(size_t)c * HW];
#pragma unroll
    for (int r = 0; r < RED; ++r) a = fmaf(Wp[c * RED + r], cr[r], a);
    oc[(size_t)c * HW] = a;
  }
}

extern "C" void kernel_launch(void* const* d_in, const int* in_sizes, int n_in,
                              void* d_out, int out_size, void* d_ws, size_t ws_size,
                              hipStream_t stream) {
  const float* x  = (const float*)d_in[0];
  const float* Wr = (const float*)d_in[1];
  const float* Wp = (const float*)d_in[2];
  float* out = (float*)d_out;

  float* feat   = (float*)d_ws;               // NPIX*32 floats
  float* rnorms = feat + (size_t)NPIX * RED;  // NPIX floats

  reduce_kern<<<NPIX / 64, 512, 0, stream>>>(x, Wr, feat, rnorms);

  dim3 g(WWX / TX, HH / TY, BB);
  corr_kern<<<g, 512, 0, stream>>>(x, Wp, feat, rnorms, out);
}